// Round 14
// baseline (744.101 us; speedup 1.0000x reference)
//
#include <hip/hip_runtime.h>
#include <hip/hip_bf16.h>

typedef __attribute__((ext_vector_type(8))) unsigned short u16x8;
typedef __attribute__((ext_vector_type(8))) __bf16 bf16x8;
typedef __attribute__((ext_vector_type(4))) unsigned uint32x4;
typedef __attribute__((ext_vector_type(2))) unsigned uint32x2;
typedef __attribute__((ext_vector_type(16))) float f32x16;

// pack two f32 -> two bf16 (round-half-up): 2 adds + 1 v_perm_b32
__device__ __forceinline__ unsigned pack_bf2(float lo, float hi) {
  unsigned a = __float_as_uint(lo) + 0x8000u;
  unsigned b = __float_as_uint(hi) + 0x8000u;
  return __builtin_amdgcn_perm(b, a, 0x07060302);
}

__device__ __forceinline__ unsigned short f2bf(float f) {
  unsigned u = __float_as_uint(f);
  return (unsigned short)((u + 0x7fffu + ((u >> 16) & 1u)) >> 16);  // RNE (prep only)
}

// ---- weights+bias pack into the 32x32-MFMA A-fragment layout + XCD-partitioned hist ----
// Layout per layer: [(t*(S+1)+s)*64 + h*32 + r]*8 + j  (bf16 elems), pad step s=S holds bias
// at (h=0,j=0). Layer bases (elems): L1=0(T2,S5) L2=5120(T4,S5) L3=15360(T2,S9) L4=24576(T1,S5).
__global__ __launch_bounds__(256)
void prep_hist(const float* __restrict__ W1, const float* __restrict__ W2,
               const float* __restrict__ W3, const float* __restrict__ W4,
               const float* __restrict__ b1, const float* __restrict__ b2,
               const float* __restrict__ b3, const float* __restrict__ b4,
               unsigned short* __restrict__ wt,
               const int* __restrict__ ei, int* __restrict__ histI, int E, int N) {
  const int tid = threadIdx.x;
  const int i = blockIdx.x * 256 + tid;
  if (i < 22816) {
    int o; float v;
    if (i < 22528) {
      int n, k, S, base;
      if (i < 4096)       { n = i >> 6;           k = i & 63;  S = 5; base = 0;     v = W1[k * 64 + n]; }
      else if (i < 12288) { int j = i - 4096;  n = j >> 6;  k = j & 63;  S = 5; base = 5120;  v = W2[k * 128 + n]; }
      else if (i < 20480) { int j = i - 12288; n = j >> 7;  k = j & 127; S = 9; base = 15360; v = W3[k * 64 + n]; }
      else                { int j = i - 20480; n = j >> 6;  k = j & 63;  S = 5; base = 24576; v = W4[k * 32 + n]; }
      const int t = n >> 5, r = n & 31, s = k >> 4, hh = (k >> 3) & 1, jj = k & 7;
      o = base + ((t * S + s) * 64 + hh * 32 + r) * 8 + jj;
    } else {
      const int i2 = i - 22528;
      if (i2 < 64)       { int q = i2;       int t = q >> 5, r = q & 31; o = 0     + ((t * 5 + 4) * 64 + r) * 8; v = b1[q]; }
      else if (i2 < 192) { int q = i2 - 64;  int t = q >> 5, r = q & 31; o = 5120  + ((t * 5 + 4) * 64 + r) * 8; v = b2[q]; }
      else if (i2 < 256) { int q = i2 - 192; int t = q >> 5, r = q & 31; o = 15360 + ((t * 9 + 8) * 64 + r) * 8; v = b3[q]; }
      else               { int q = i2 - 256; int t = q >> 5, r = q & 31; o = 24576 + ((t * 5 + 4) * 64 + r) * 8; v = b4[q]; }
    }
    wt[o] = f2bf(v);
  }
  const int xcd = blockIdx.x & 7, kblk = blockIdx.x >> 3;
  const int nchunks = gridDim.x >> 3;
  const int chunk = (((E + nchunks - 1) / nchunks) + 3) & ~3;
  const int eBeg = kblk * chunk;
  const int eEnd = min(eBeg + chunk, E);
  const int dLo = (int)((long)xcd * N / 8);
  const int dHi = (int)((long)(xcd + 1) * N / 8);
  int e0 = eBeg + tid * 4;
  for (; e0 + 3 < eEnd; e0 += 1024) {
    const int4 d4 = *(const int4*)(ei + E + e0);
    if (d4.x >= dLo && d4.x < dHi) atomicAdd(&histI[d4.x], 1);
    if (d4.y >= dLo && d4.y < dHi) atomicAdd(&histI[d4.y], 1);
    if (d4.z >= dLo && d4.z < dHi) atomicAdd(&histI[d4.z], 1);
    if (d4.w >= dLo && d4.w < dHi) atomicAdd(&histI[d4.w], 1);
  }
  for (int e = e0; e < eEnd; ++e) {
    const int d = ei[E + e];
    if (d >= dLo && d < dHi) atomicAdd(&histI[d], 1);
  }
}

// per-block exclusive scan of 2048 elems (256 thr x 8), write per-block totals
__global__ void scan_blocks(const int* __restrict__ histI, int* __restrict__ row_start,
                            int* __restrict__ blockSums, int N) {
  __shared__ int wsum[4];
  const int lane = threadIdx.x & 63, w = threadIdx.x >> 6;
  const int i0 = blockIdx.x * 2048 + threadIdx.x * 8;
  int v[8];
#pragma unroll
  for (int j = 0; j < 8; ++j) { int i = i0 + j; v[j] = (i < N) ? histI[i] : 0; }
  int s = 0;
#pragma unroll
  for (int j = 0; j < 8; ++j) { int t = v[j]; v[j] = s; s += t; }
  int ss = s;
#pragma unroll
  for (int d = 1; d < 64; d <<= 1) { int t = __shfl_up(ss, d, 64); if (lane >= d) ss += t; }
  if (lane == 63) wsum[w] = ss;
  __syncthreads();
  int wOff = 0;
#pragma unroll
  for (int k = 0; k < 4; ++k) if (k < w) wOff += wsum[k];
  const int tOff = wOff + (ss - s);
#pragma unroll
  for (int j = 0; j < 8; ++j) { int i = i0 + j; if (i < N) row_start[i] = tOff + v[j]; }
  if (threadIdx.x == 255) blockSums[blockIdx.x] = wOff + ss;
}

// ---- XCD-partitioned CSR fill; slot allocation via atomicAdd on row_start itself ----
__global__ __launch_bounds__(256)
void fill_kernel(const int* __restrict__ ei, int* __restrict__ row_start,
                 const int* __restrict__ blockSums, int2* __restrict__ edlist,
                 float* __restrict__ out, int E, int N, int nb) {
  __shared__ int spre[32];
  if (threadIdx.x == 0) {
    int acc = 0;
    for (int k = 0; k < nb; ++k) { spre[k] = acc; acc += blockSums[k]; }
  }
  __syncthreads();
  const int tid = threadIdx.x;
  const int Ntot4 = N * 8;
  for (int i = blockIdx.x * 256 + tid; i < Ntot4; i += gridDim.x * 256)
    ((float4*)out)[i] = make_float4(0.f, 0.f, 0.f, 0.f);

  const int xcd = blockIdx.x & 7, kblk = blockIdx.x >> 3;
  const int nchunks = gridDim.x >> 3;
  const int chunk = (((E + nchunks - 1) / nchunks) + 3) & ~3;
  const int eBeg = kblk * chunk;
  const int eEnd = min(eBeg + chunk, E);
  const int dLo = (int)((long)xcd * N / 8);
  const int dHi = (int)((long)(xcd + 1) * N / 8);
  int e0 = eBeg + tid * 4;
  for (; e0 + 3 < eEnd; e0 += 1024) {
    const int4 d4 = *(const int4*)(ei + E + e0);
    const int dv[4] = {d4.x, d4.y, d4.z, d4.w};
#pragma unroll
    for (int j = 0; j < 4; ++j) {
      const int d = dv[j];
      if (d >= dLo && d < dHi) {
        const int pos = atomicAdd(&row_start[d], 1) + spre[d >> 11];
        edlist[pos] = make_int2(e0 + j, d);
      }
    }
  }
  for (int e = e0; e < eEnd; ++e) {
    const int d = ei[E + e];
    if (d >= dLo && d < dHi) {
      const int pos = atomicAdd(&row_start[d], 1) + spre[d >> 11];
      edlist[pos] = make_int2(e, d);
    }
  }
}

// ---- C(32x32 f32x16) -> two B-fragments of the next layer (relu fused, in-register) ----
// C layout: col=lane&31, row=(reg&3)+8*(reg>>2)+4*(lane>>5).  B needs k=(lane>>5)*8+j.
// lane l and l+32 hold the same col -> one permlane32_swap per word pair completes 8 rows.
__device__ __forceinline__ void c2frag(const f32x16 a, uint32x4& f0, uint32x4& f1) {
  unsigned u[8];
#pragma unroll
  for (int q = 0; q < 4; ++q) {
    u[2 * q]     = pack_bf2(fmaxf(a[4 * q + 0], 0.f), fmaxf(a[4 * q + 1], 0.f));
    u[2 * q + 1] = pack_bf2(fmaxf(a[4 * q + 2], 0.f), fmaxf(a[4 * q + 3], 0.f));
  }
  const uint32x2 r0 = __builtin_amdgcn_permlane32_swap(u[0], u[2], false, false);
  const uint32x2 r1 = __builtin_amdgcn_permlane32_swap(u[1], u[3], false, false);
  const uint32x2 r2 = __builtin_amdgcn_permlane32_swap(u[4], u[6], false, false);
  const uint32x2 r3 = __builtin_amdgcn_permlane32_swap(u[5], u[7], false, false);
  f0[0] = r0[0]; f0[1] = r1[0]; f0[2] = r0[1]; f0[3] = r1[1];
  f1[0] = r2[0]; f1[1] = r3[0]; f1[2] = r2[1]; f1[3] = r3[1];
}

// one layer: T output 32-tiles, S real k-steps + 1 bias-pad step; emits next-layer B-frags
template <int T, int S>
__device__ __forceinline__ void layerC(const unsigned char* wl, const uint32x4* bin,
                                       const uint32x4 padf, uint32x4* bout, int lane) {
#pragma unroll
  for (int t = 0; t < T; ++t) {
    f32x16 a = {};
    __builtin_amdgcn_s_setprio(1);
#pragma unroll
    for (int s = 0; s <= S; ++s) {
      const u16x8 af = *(const u16x8*)(wl + (size_t)((t * (S + 1) + s) * 64 + lane) * 16);
      const uint32x4 bb = (s < S) ? bin[s] : padf;
      a = __builtin_amdgcn_mfma_f32_32x32x16_bf16(
          __builtin_bit_cast(bf16x8, af), __builtin_bit_cast(bf16x8, bb), a, 0, 0, 0);
    }
    __builtin_amdgcn_s_setprio(0);
    c2frag(a, bout[2 * t], bout[2 * t + 1]);
  }
}

__device__ __forceinline__ f32x16 layer4(const unsigned char* wl, const uint32x4* bin,
                                         const uint32x4 padf, int lane) {
  f32x16 a = {};
  __builtin_amdgcn_s_setprio(1);
#pragma unroll
  for (int s = 0; s <= 4; ++s) {
    const u16x8 af = *(const u16x8*)(wl + (size_t)(s * 64 + lane) * 16);
    const uint32x4 bb = (s < 4) ? bin[s] : padf;
    a = __builtin_amdgcn_mfma_f32_32x32x16_bf16(
        __builtin_bit_cast(bf16x8, af), __builtin_bit_cast(bf16x8, bb), a, 0, 0, 0);
  }
  __builtin_amdgcn_s_setprio(0);
  return a;
}

__device__ __forceinline__ uint32x4 pk8(const float4& a, const float4& b) {
  uint32x4 r;
  r[0] = pack_bf2(a.x, a.y); r[1] = pack_bf2(a.z, a.w);
  r[2] = pack_bf2(b.x, b.y); r[3] = pack_bf2(b.z, b.w);
  return r;
}

// gather one 32-edge tile: lane owns edge lane&31, loads its h-half of x and ea (4x float4 each)
__device__ __forceinline__ void load_tile32(int pbase, int E, const int2* __restrict__ edlist,
                                            const float* __restrict__ x, const float* __restrict__ ea,
                                            const int* __restrict__ histI, int lane,
                                            float4 (&px)[4], float4 (&pe)[4], int& dstA, int& cntA) {
  const int pos = pbase + (lane & 31);
  const int h = lane >> 5;
#pragma unroll
  for (int j = 0; j < 4; ++j) { px[j] = make_float4(0.f, 0.f, 0.f, 0.f); pe[j] = px[j]; }
  dstA = -1; cntA = 1;
  if (pos < E) {
    const int2 ed = edlist[pos];
    dstA = ed.y; cntA = histI[ed.y];
    const float4* xp = (const float4*)(x + (size_t)ed.y * 32);
    const float4* ep = (const float4*)(ea + (size_t)ed.x * 32);
    px[0] = xp[2 * h]; px[1] = xp[2 * h + 1]; px[2] = xp[4 + 2 * h]; px[3] = xp[5 + 2 * h];
    pe[0] = ep[2 * h]; pe[1] = ep[2 * h + 1]; pe[2] = ep[4 + 2 * h]; pe[3] = ep[5 + 2 * h];
  }
}

// LDS: pure weights, 54272 B (53 KB) -> 3 blocks/CU at 256 thr
__global__ __launch_bounds__(256, 3)
void gnn_main(const float* __restrict__ x, const int2* __restrict__ edlist,
              const float* __restrict__ ea, const unsigned short* __restrict__ wt,
              const int* __restrict__ histI, float* __restrict__ out, int E, int numTiles) {
  __shared__ __align__(16) unsigned char lds[54272];
  {
    const u16x8* gw = (const u16x8*)wt;
    u16x8* lw = (u16x8*)lds;
    for (int i = threadIdx.x; i < 3392; i += 256) lw[i] = gw[i];
  }
  __syncthreads();

  const int lane = threadIdx.x & 63, wid = threadIdx.x >> 6;
  const unsigned char* wl1 = lds;
  const unsigned char* wl2 = lds + 10240;
  const unsigned char* wl3 = lds + 30720;
  const unsigned char* wl4 = lds + 49152;

  // constant-1 bf16 B-fragment for the bias pad step (k = S*16: h=0, j=0)
  uint32x4 padf;
  padf[0] = (lane < 32) ? 0x3F80u : 0u;
  padf[1] = 0u; padf[2] = 0u; padf[3] = 0u;

  const int wgl = blockIdx.x * 4 + wid;
  const int wstride = gridDim.x * 4;

  float4 px[4], pe[4]; int dstA = -1, cntA = 1;
  if (wgl < numTiles) load_tile32(wgl * 32, E, edlist, x, ea, histI, lane, px, pe, dstA, cntA);

  for (int tile = wgl; tile < numTiles; tile += wstride) {
    // pack H0 (concat(x,ea)) into 4 B-fragments, all in registers
    uint32x4 b0[4];
    b0[0] = pk8(px[0], px[1]);
    b0[1] = pk8(px[2], px[3]);
    b0[2] = pk8(pe[0], pe[1]);
    b0[3] = pk8(pe[2], pe[3]);
    const int curDst = dstA, curCnt = cntA;

    // issue next tile's gather; drains under the MFMA chain
    const int nt = tile + wstride;
    float4 npx[4], npe[4]; int nd = -1, nc = 1;
    if (nt < numTiles) load_tile32(nt * 32, E, edlist, x, ea, histI, lane, npx, npe, nd, nc);
    else {
#pragma unroll
      for (int j = 0; j < 4; ++j) { npx[j] = make_float4(0.f, 0.f, 0.f, 0.f); npe[j] = npx[j]; }
    }

    uint32x4 b1[4], b2[8], b3[4];
    layerC<2, 4>(wl1, b0, padf, b1, lane);   // 64 -> 64
    layerC<4, 4>(wl2, b1, padf, b2, lane);   // 64 -> 128
    layerC<2, 8>(wl3, b2, padf, b3, lane);   // 128 -> 64
    const f32x16 a4 = layer4(wl4, b3, padf, lane);  // 64 -> 32

    float vals[16];
#pragma unroll
    for (int r = 0; r < 16; ++r) vals[r] = fmaxf(a4[r], 0.f);

    // segmented sum over the 32-edge lane dim (CSR order => equal dsts adjacent)
    const int e32 = lane & 31;
    const int prev = __shfl_up(curDst, 1, 32);
    const bool is_head = (e32 == 0) || (prev != curDst);
    const unsigned long long hb = __ballot(is_head);
    const unsigned gm = (unsigned)(hb >> ((lane >> 5) << 5));
    const unsigned below = gm & ((1u << e32) | ((1u << e32) - 1u));
    const int dist = e32 - (31 - __clz(below));
#pragma unroll
    for (int d = 1; d < 32; d <<= 1) {
#pragma unroll
      for (int r = 0; r < 16; ++r) {
        const float tv = __shfl_up(vals[r], d, 32);
        if (dist >= d) vals[r] += tv;
      }
    }
    const bool is_end = (e32 == 31) || ((gm >> (e32 + 1)) & 1u);
    if (is_end && curDst >= 0) {
      const float inv = 1.0f / (float)curCnt;   // mean fused into scatter
      float* op = out + (size_t)curDst * 32 + 4 * (lane >> 5);
#pragma unroll
      for (int r = 0; r < 16; ++r)
        unsafeAtomicAdd(op + (r & 3) + 8 * (r >> 2), vals[r] * inv);
    }

#pragma unroll
    for (int j = 0; j < 4; ++j) { px[j] = npx[j]; pe[j] = npe[j]; }
    dstA = nd; cntA = nc;
  }
}

extern "C" void kernel_launch(void* const* d_in, const int* in_sizes, int n_in,
                              void* d_out, int out_size, void* d_ws, size_t ws_size,
                              hipStream_t stream) {
  const float* x  = (const float*)d_in[0];
  const int*   ei = (const int*)d_in[1];
  const float* ea = (const float*)d_in[2];
  const float* W1 = (const float*)d_in[3];
  const float* b1 = (const float*)d_in[4];
  const float* W2 = (const float*)d_in[5];
  const float* b2 = (const float*)d_in[6];
  const float* W3 = (const float*)d_in[7];
  const float* b3 = (const float*)d_in[8];
  const float* W4 = (const float*)d_in[9];
  const float* b4 = (const float*)d_in[10];
  const int N = in_sizes[0] / 32;
  const int E = in_sizes[1] / 2;
  float* out = (float*)d_out;

  char* ws = (char*)d_ws;
  size_t off = 0;
  auto alloc = [&](size_t bytes) { size_t o = off; off += (bytes + 255) & ~(size_t)255; return o; };
  size_t hist_off = alloc((size_t)N * 4);
  size_t wt_off   = alloc(27136 * 2);           // padded A-fragment weight buffer (needs zeroing)
  int* histI      = (int*)(ws + hist_off);
  unsigned short* wt = (unsigned short*)(ws + wt_off);
  int* row_start  = (int*)(ws + alloc((size_t)(N + 1) * 4));
  int* blockSums  = (int*)(ws + alloc(256 * 4));
  int2* edlist    = (int2*)(ws + alloc((size_t)E * 8));

  // one memset zeroes histI + wt (adjacent)
  hipMemsetAsync(ws + hist_off, 0, (wt_off - hist_off) + 27136 * 2, stream);

  prep_hist<<<2048, 256, 0, stream>>>(W1, W2, W3, W4, b1, b2, b3, b4, wt, ei, histI, E, N);
  const int nb = (N + 2047) / 2048;
  scan_blocks<<<nb, 256, 0, stream>>>(histI, row_start, blockSums, N);
  fill_kernel<<<2048, 256, 0, stream>>>(ei, row_start, blockSums, edlist, out, E, N, nb);
  const int numTiles = (E + 31) / 32;
  gnn_main<<<768, 256, 0, stream>>>(x, edlist, ea, wt, histI, out, E, numTiles);
}

// Round 15
// 731.181 us; speedup vs baseline: 1.0177x; 1.0177x over previous
//
#include <hip/hip_runtime.h>
#include <hip/hip_bf16.h>

typedef __attribute__((ext_vector_type(8))) unsigned short u16x8;
typedef __attribute__((ext_vector_type(8))) __bf16 bf16x8;
typedef __attribute__((ext_vector_type(4))) unsigned uint32x4;
typedef __attribute__((ext_vector_type(2))) unsigned uint32x2;
typedef __attribute__((ext_vector_type(16))) float f32x16;

// pack two f32 -> two bf16 (round-half-up): 2 adds + 1 v_perm_b32
__device__ __forceinline__ unsigned pack_bf2(float lo, float hi) {
  unsigned a = __float_as_uint(lo) + 0x8000u;
  unsigned b = __float_as_uint(hi) + 0x8000u;
  return __builtin_amdgcn_perm(b, a, 0x07060302);
}

__device__ __forceinline__ unsigned short f2bf(float f) {
  unsigned u = __float_as_uint(f);
  return (unsigned short)((u + 0x7fffu + ((u >> 16) & 1u)) >> 16);  // RNE (prep only)
}

// ---- weights+bias pack into the 32x32-MFMA A-fragment layout + XCD-partitioned hist ----
// Layout per layer: [(t*(S+1)+s)*64 + h*32 + r]*8 + j  (bf16 elems), pad step s=S holds bias
// at (h=0,j=0). Layer bases (elems): L1=0(T2,S5) L2=5120(T4,S5) L3=15360(T2,S9) L4=24576(T1,S5).
__global__ __launch_bounds__(256)
void prep_hist(const float* __restrict__ W1, const float* __restrict__ W2,
               const float* __restrict__ W3, const float* __restrict__ W4,
               const float* __restrict__ b1, const float* __restrict__ b2,
               const float* __restrict__ b3, const float* __restrict__ b4,
               unsigned short* __restrict__ wt,
               const int* __restrict__ ei, int* __restrict__ histI, int E, int N) {
  const int tid = threadIdx.x;
  const int i = blockIdx.x * 256 + tid;
  if (i < 22816) {
    int o; float v;
    if (i < 22528) {
      int n, k, S, base;
      if (i < 4096)       { n = i >> 6;           k = i & 63;  S = 5; base = 0;     v = W1[k * 64 + n]; }
      else if (i < 12288) { int j = i - 4096;  n = j >> 6;  k = j & 63;  S = 5; base = 5120;  v = W2[k * 128 + n]; }
      else if (i < 20480) { int j = i - 12288; n = j >> 7;  k = j & 127; S = 9; base = 15360; v = W3[k * 64 + n]; }
      else                { int j = i - 20480; n = j >> 6;  k = j & 63;  S = 5; base = 24576; v = W4[k * 32 + n]; }
      const int t = n >> 5, r = n & 31, s = k >> 4, hh = (k >> 3) & 1, jj = k & 7;
      o = base + ((t * S + s) * 64 + hh * 32 + r) * 8 + jj;
    } else {
      const int i2 = i - 22528;
      if (i2 < 64)       { int q = i2;       int t = q >> 5, r = q & 31; o = 0     + ((t * 5 + 4) * 64 + r) * 8; v = b1[q]; }
      else if (i2 < 192) { int q = i2 - 64;  int t = q >> 5, r = q & 31; o = 5120  + ((t * 5 + 4) * 64 + r) * 8; v = b2[q]; }
      else if (i2 < 256) { int q = i2 - 192; int t = q >> 5, r = q & 31; o = 15360 + ((t * 9 + 8) * 64 + r) * 8; v = b3[q]; }
      else               { int q = i2 - 256; int t = q >> 5, r = q & 31; o = 24576 + ((t * 5 + 4) * 64 + r) * 8; v = b4[q]; }
    }
    wt[o] = f2bf(v);
  }
  const int xcd = blockIdx.x & 7, kblk = blockIdx.x >> 3;
  const int nchunks = gridDim.x >> 3;
  const int chunk = (((E + nchunks - 1) / nchunks) + 3) & ~3;
  const int eBeg = kblk * chunk;
  const int eEnd = min(eBeg + chunk, E);
  const int dLo = (int)((long)xcd * N / 8);
  const int dHi = (int)((long)(xcd + 1) * N / 8);
  int e0 = eBeg + tid * 4;
  for (; e0 + 3 < eEnd; e0 += 1024) {
    const int4 d4 = *(const int4*)(ei + E + e0);
    if (d4.x >= dLo && d4.x < dHi) atomicAdd(&histI[d4.x], 1);
    if (d4.y >= dLo && d4.y < dHi) atomicAdd(&histI[d4.y], 1);
    if (d4.z >= dLo && d4.z < dHi) atomicAdd(&histI[d4.z], 1);
    if (d4.w >= dLo && d4.w < dHi) atomicAdd(&histI[d4.w], 1);
  }
  for (int e = e0; e < eEnd; ++e) {
    const int d = ei[E + e];
    if (d >= dLo && d < dHi) atomicAdd(&histI[d], 1);
  }
}

// per-block exclusive scan of 2048 elems (256 thr x 8), write per-block totals
__global__ void scan_blocks(const int* __restrict__ histI, int* __restrict__ row_start,
                            int* __restrict__ blockSums, int N) {
  __shared__ int wsum[4];
  const int lane = threadIdx.x & 63, w = threadIdx.x >> 6;
  const int i0 = blockIdx.x * 2048 + threadIdx.x * 8;
  int v[8];
#pragma unroll
  for (int j = 0; j < 8; ++j) { int i = i0 + j; v[j] = (i < N) ? histI[i] : 0; }
  int s = 0;
#pragma unroll
  for (int j = 0; j < 8; ++j) { int t = v[j]; v[j] = s; s += t; }
  int ss = s;
#pragma unroll
  for (int d = 1; d < 64; d <<= 1) { int t = __shfl_up(ss, d, 64); if (lane >= d) ss += t; }
  if (lane == 63) wsum[w] = ss;
  __syncthreads();
  int wOff = 0;
#pragma unroll
  for (int k = 0; k < 4; ++k) if (k < w) wOff += wsum[k];
  const int tOff = wOff + (ss - s);
#pragma unroll
  for (int j = 0; j < 8; ++j) { int i = i0 + j; if (i < N) row_start[i] = tOff + v[j]; }
  if (threadIdx.x == 255) blockSums[blockIdx.x] = wOff + ss;
}

// ---- XCD-partitioned CSR fill; slot allocation via atomicAdd on row_start itself ----
__global__ __launch_bounds__(256)
void fill_kernel(const int* __restrict__ ei, int* __restrict__ row_start,
                 const int* __restrict__ blockSums, int2* __restrict__ edlist,
                 float* __restrict__ out, int E, int N, int nb) {
  __shared__ int spre[32];
  if (threadIdx.x == 0) {
    int acc = 0;
    for (int k = 0; k < nb; ++k) { spre[k] = acc; acc += blockSums[k]; }
  }
  __syncthreads();
  const int tid = threadIdx.x;
  const int Ntot4 = N * 8;
  for (int i = blockIdx.x * 256 + tid; i < Ntot4; i += gridDim.x * 256)
    ((float4*)out)[i] = make_float4(0.f, 0.f, 0.f, 0.f);

  const int xcd = blockIdx.x & 7, kblk = blockIdx.x >> 3;
  const int nchunks = gridDim.x >> 3;
  const int chunk = (((E + nchunks - 1) / nchunks) + 3) & ~3;
  const int eBeg = kblk * chunk;
  const int eEnd = min(eBeg + chunk, E);
  const int dLo = (int)((long)xcd * N / 8);
  const int dHi = (int)((long)(xcd + 1) * N / 8);
  int e0 = eBeg + tid * 4;
  for (; e0 + 3 < eEnd; e0 += 1024) {
    const int4 d4 = *(const int4*)(ei + E + e0);
    const int dv[4] = {d4.x, d4.y, d4.z, d4.w};
#pragma unroll
    for (int j = 0; j < 4; ++j) {
      const int d = dv[j];
      if (d >= dLo && d < dHi) {
        const int pos = atomicAdd(&row_start[d], 1) + spre[d >> 11];
        edlist[pos] = make_int2(e0 + j, d);
      }
    }
  }
  for (int e = e0; e < eEnd; ++e) {
    const int d = ei[E + e];
    if (d >= dLo && d < dHi) {
      const int pos = atomicAdd(&row_start[d], 1) + spre[d >> 11];
      edlist[pos] = make_int2(e, d);
    }
  }
}

// ---- C(32x32 f32x16) -> two B-fragments of the next layer (relu fused, in-register) ----
__device__ __forceinline__ void c2frag(const f32x16 a, uint32x4& f0, uint32x4& f1) {
  unsigned u[8];
#pragma unroll
  for (int q = 0; q < 4; ++q) {
    u[2 * q]     = pack_bf2(fmaxf(a[4 * q + 0], 0.f), fmaxf(a[4 * q + 1], 0.f));
    u[2 * q + 1] = pack_bf2(fmaxf(a[4 * q + 2], 0.f), fmaxf(a[4 * q + 3], 0.f));
  }
  const uint32x2 r0 = __builtin_amdgcn_permlane32_swap(u[0], u[2], false, false);
  const uint32x2 r1 = __builtin_amdgcn_permlane32_swap(u[1], u[3], false, false);
  const uint32x2 r2 = __builtin_amdgcn_permlane32_swap(u[4], u[6], false, false);
  const uint32x2 r3 = __builtin_amdgcn_permlane32_swap(u[5], u[7], false, false);
  f0[0] = r0[0]; f0[1] = r1[0]; f0[2] = r0[1]; f0[3] = r1[1];
  f1[0] = r2[0]; f1[1] = r3[0]; f1[2] = r2[1]; f1[3] = r3[1];
}

// one layer: T output 32-tiles, S real k-steps + 1 bias-pad step; emits next-layer B-frags
template <int T, int S>
__device__ __forceinline__ void layerC(const unsigned char* wl, const uint32x4* bin,
                                       const uint32x4 padf, uint32x4* bout, int lane) {
#pragma unroll
  for (int t = 0; t < T; ++t) {
    f32x16 a = {};
    __builtin_amdgcn_s_setprio(1);
#pragma unroll
    for (int s = 0; s <= S; ++s) {
      const u16x8 af = *(const u16x8*)(wl + (size_t)((t * (S + 1) + s) * 64 + lane) * 16);
      const uint32x4 bb = (s < S) ? bin[s] : padf;
      a = __builtin_amdgcn_mfma_f32_32x32x16_bf16(
          __builtin_bit_cast(bf16x8, af), __builtin_bit_cast(bf16x8, bb), a, 0, 0, 0);
    }
    __builtin_amdgcn_s_setprio(0);
    c2frag(a, bout[2 * t], bout[2 * t + 1]);
  }
}

__device__ __forceinline__ f32x16 layer4(const unsigned char* wl, const uint32x4* bin,
                                         const uint32x4 padf, int lane) {
  f32x16 a = {};
  __builtin_amdgcn_s_setprio(1);
#pragma unroll
  for (int s = 0; s <= 4; ++s) {
    const u16x8 af = *(const u16x8*)(wl + (size_t)(s * 64 + lane) * 16);
    const uint32x4 bb = (s < 4) ? bin[s] : padf;
    a = __builtin_amdgcn_mfma_f32_32x32x16_bf16(
        __builtin_bit_cast(bf16x8, af), __builtin_bit_cast(bf16x8, bb), a, 0, 0, 0);
  }
  __builtin_amdgcn_s_setprio(0);
  return a;
}

__device__ __forceinline__ uint32x4 pk8(const float4& a, const float4& b) {
  uint32x4 r;
  r[0] = pack_bf2(a.x, a.y); r[1] = pack_bf2(a.z, a.w);
  r[2] = pack_bf2(b.x, b.y); r[3] = pack_bf2(b.z, b.w);
  return r;
}

// gather one 32-edge tile, packing straight to bf16 B-fragments (16 VGPRs, not 32)
__device__ __forceinline__ void load_tile32(int pbase, int E, const int2* __restrict__ edlist,
                                            const float* __restrict__ x, const float* __restrict__ ea,
                                            const int* __restrict__ histI, int lane,
                                            uint32x4 (&b0)[4], int& dstA, int& cntA) {
  const int pos = pbase + (lane & 31);
  const int h = lane >> 5;
#pragma unroll
  for (int j = 0; j < 4; ++j) b0[j] = (uint32x4){0u, 0u, 0u, 0u};
  dstA = -1; cntA = 1;
  if (pos < E) {
    const int2 ed = edlist[pos];
    dstA = ed.y; cntA = histI[ed.y];
    const float4* xp = (const float4*)(x + (size_t)ed.y * 32);
    const float4* ep = (const float4*)(ea + (size_t)ed.x * 32);
    {
      const float4 t0 = xp[2 * h], t1 = xp[2 * h + 1];
      b0[0] = pk8(t0, t1);
    }
    {
      const float4 t0 = xp[4 + 2 * h], t1 = xp[5 + 2 * h];
      b0[1] = pk8(t0, t1);
    }
    {
      const float4 t0 = ep[2 * h], t1 = ep[2 * h + 1];
      b0[2] = pk8(t0, t1);
    }
    {
      const float4 t0 = ep[4 + 2 * h], t1 = ep[5 + 2 * h];
      b0[3] = pk8(t0, t1);
    }
  }
}

// LDS: pure weights, 54272 B -> 3 blocks/CU at 256 thr
__global__ __launch_bounds__(256, 3)
void gnn_main(const float* __restrict__ x, const int2* __restrict__ edlist,
              const float* __restrict__ ea, const unsigned short* __restrict__ wt,
              const int* __restrict__ histI, float* __restrict__ out, int E, int numTiles) {
  __shared__ __align__(16) unsigned char lds[54272];
  {
    const u16x8* gw = (const u16x8*)wt;
    u16x8* lw = (u16x8*)lds;
    for (int i = threadIdx.x; i < 3392; i += 256) lw[i] = gw[i];
  }
  __syncthreads();

  const int lane = threadIdx.x & 63, wid = threadIdx.x >> 6;
  const unsigned char* wl1 = lds;
  const unsigned char* wl2 = lds + 10240;
  const unsigned char* wl3 = lds + 30720;
  const unsigned char* wl4 = lds + 49152;

  // constant-1 bf16 B-fragment for the bias pad step (k = S*16: h=0, j=0)
  uint32x4 padf;
  padf[0] = (lane < 32) ? 0x3F80u : 0u;
  padf[1] = 0u; padf[2] = 0u; padf[3] = 0u;

  const int wgl = blockIdx.x * 4 + wid;
  const int wstride = gridDim.x * 4;

  uint32x4 b0[4]; int dstA = -1, cntA = 1;
  if (wgl < numTiles) load_tile32(wgl * 32, E, edlist, x, ea, histI, lane, b0, dstA, cntA);

  for (int tile = wgl; tile < numTiles; tile += wstride) {
    const int curDst = dstA, curCnt = cntA;

    // issue next tile's gather (packed form, 16 regs); drains under the MFMA chain
    const int nt = tile + wstride;
    uint32x4 nb0[4]; int nd = -1, nc = 1;
    if (nt < numTiles) load_tile32(nt * 32, E, edlist, x, ea, histI, lane, nb0, nd, nc);
    else {
#pragma unroll
      for (int j = 0; j < 4; ++j) nb0[j] = (uint32x4){0u, 0u, 0u, 0u};
    }

    uint32x4 b1[4], b2[8], b3[4];
    layerC<2, 4>(wl1, b0, padf, b1, lane);   // 64 -> 64
    layerC<4, 4>(wl2, b1, padf, b2, lane);   // 64 -> 128
    layerC<2, 8>(wl3, b2, padf, b3, lane);   // 128 -> 64
    f32x16 a4 = layer4(wl4, b3, padf, lane); // 64 -> 32

#pragma unroll
    for (int r = 0; r < 16; ++r) a4[r] = fmaxf(a4[r], 0.f);

    // segmented sum over the 32-edge lane dim (CSR order => equal dsts adjacent)
    const int e32 = lane & 31;
    const int prev = __shfl_up(curDst, 1, 32);
    const bool is_head = (e32 == 0) || (prev != curDst);
    const unsigned long long hb = __ballot(is_head);
    const unsigned gm = (unsigned)(hb >> ((lane >> 5) << 5));
    const unsigned below = gm & ((1u << e32) | ((1u << e32) - 1u));
    const int dist = e32 - (31 - __clz(below));
#pragma unroll
    for (int d = 1; d < 32; d <<= 1) {
#pragma unroll
      for (int r = 0; r < 16; ++r) {
        const float tv = __shfl_up(a4[r], d, 32);
        if (dist >= d) a4[r] += tv;
      }
    }
    const bool is_end = (e32 == 31) || ((gm >> (e32 + 1)) & 1u);
    if (is_end && curDst >= 0) {
      const float inv = 1.0f / (float)curCnt;   // mean fused into scatter
      float* op = out + (size_t)curDst * 32 + 4 * (lane >> 5);
#pragma unroll
      for (int r = 0; r < 16; ++r)
        unsafeAtomicAdd(op + (r & 3) + 8 * (r >> 2), a4[r] * inv);
    }

#pragma unroll
    for (int j = 0; j < 4; ++j) b0[j] = nb0[j];
    dstA = nd; cntA = nc;
  }
}

extern "C" void kernel_launch(void* const* d_in, const int* in_sizes, int n_in,
                              void* d_out, int out_size, void* d_ws, size_t ws_size,
                              hipStream_t stream) {
  const float* x  = (const float*)d_in[0];
  const int*   ei = (const int*)d_in[1];
  const float* ea = (const float*)d_in[2];
  const float* W1 = (const float*)d_in[3];
  const float* b1 = (const float*)d_in[4];
  const float* W2 = (const float*)d_in[5];
  const float* b2 = (const float*)d_in[6];
  const float* W3 = (const float*)d_in[7];
  const float* b3 = (const float*)d_in[8];
  const float* W4 = (const float*)d_in[9];
  const float* b4 = (const float*)d_in[10];
  const int N = in_sizes[0] / 32;
  const int E = in_sizes[1] / 2;
  float* out = (float*)d_out;

  char* ws = (char*)d_ws;
  size_t off = 0;
  auto alloc = [&](size_t bytes) { size_t o = off; off += (bytes + 255) & ~(size_t)255; return o; };
  size_t hist_off = alloc((size_t)N * 4);
  size_t wt_off   = alloc(27136 * 2);           // padded A-fragment weight buffer (needs zeroing)
  int* histI      = (int*)(ws + hist_off);
  unsigned short* wt = (unsigned short*)(ws + wt_off);
  int* row_start  = (int*)(ws + alloc((size_t)(N + 1) * 4));
  int* blockSums  = (int*)(ws + alloc(256 * 4));
  int2* edlist    = (int2*)(ws + alloc((size_t)E * 8));

  // one memset zeroes histI + wt (adjacent)
  hipMemsetAsync(ws + hist_off, 0, (wt_off - hist_off) + 27136 * 2, stream);

  prep_hist<<<2048, 256, 0, stream>>>(W1, W2, W3, W4, b1, b2, b3, b4, wt, ei, histI, E, N);
  const int nb = (N + 2047) / 2048;
  scan_blocks<<<nb, 256, 0, stream>>>(histI, row_start, blockSums, N);
  fill_kernel<<<2048, 256, 0, stream>>>(ei, row_start, blockSums, edlist, out, E, N, nb);
  const int numTiles = (E + 31) / 32;
  gnn_main<<<768, 256, 0, stream>>>(x, edlist, ea, wt, histI, out, E, numTiles);
}